// Round 1
// baseline (71.408 us; speedup 1.0000x reference)
//
#include <hip/hip_runtime.h>

// MemristiveLinear reduces exactly to y = x @ w + b:
//   total_currents = sum_i v_i*(g_pos - g_neg) = sum_i (K_V x_i)(k_cond w_i)
//   y = total / (K_V * k_cond) = x @ w + b
// (G_OFF cancels in the even-odd subtraction; K_V and k_cond cancel in the
// final division, so max|weight| is never needed.)

constexpr int N_IN  = 512;
constexpr int N_OUT = 512;

__global__ __launch_bounds__(256) void memlin_gemm(
    const float* __restrict__ x,   // [B, N_IN]
    const float* __restrict__ w,   // [N_IN, N_OUT]
    const float* __restrict__ bias,// [N_OUT]
    float* __restrict__ y)         // [B, N_OUT]
{
    const int t  = threadIdx.x;
    const int br = blockIdx.y;   // row tile (32 rows of x)
    const int bc = blockIdx.x;   // col tile (32 cols of w)

    const int lr  = t >> 3;      // 0..31 : row within tile
    const int lc4 = t & 7;       // 0..7  : float4 column group

    __shared__ float xs[32][33]; // +1 pad: xs[lr][kk] column reads hit distinct banks
    __shared__ float ws[32][32]; // unpadded: keeps ds_read_b128 16B-aligned; reads are
                                 // 8 distinct 16B addrs per wave (broadcast, conflict-free)

    float acc0 = 0.f, acc1 = 0.f, acc2 = 0.f, acc3 = 0.f;

    const float* xg = x + (br * 32 + lr) * N_IN + lc4 * 4;
    const float* wg = w + lr * N_OUT + bc * 32 + lc4 * 4;

    for (int k0 = 0; k0 < N_IN; k0 += 32) {
        // stage x tile [32 rows][k0..k0+32) and w tile [k0..k0+32)[32 cols]
        const float4 xv = *reinterpret_cast<const float4*>(xg + k0);
        const float4 wv = *reinterpret_cast<const float4*>(wg + (size_t)k0 * N_OUT);

        xs[lr][lc4 * 4 + 0] = xv.x;
        xs[lr][lc4 * 4 + 1] = xv.y;
        xs[lr][lc4 * 4 + 2] = xv.z;
        xs[lr][lc4 * 4 + 3] = xv.w;
        *reinterpret_cast<float4*>(&ws[lr][lc4 * 4]) = wv;

        __syncthreads();

#pragma unroll
        for (int kk = 0; kk < 32; ++kk) {
            const float xa = xs[lr][kk];
            const float4 wr = *reinterpret_cast<const float4*>(&ws[kk][lc4 * 4]);
            acc0 = fmaf(xa, wr.x, acc0);
            acc1 = fmaf(xa, wr.y, acc1);
            acc2 = fmaf(xa, wr.z, acc2);
            acc3 = fmaf(xa, wr.w, acc3);
        }

        __syncthreads();
    }

    const float4 bv = *reinterpret_cast<const float4*>(bias + bc * 32 + lc4 * 4);
    float4 o;
    o.x = acc0 + bv.x;
    o.y = acc1 + bv.y;
    o.z = acc2 + bv.z;
    o.w = acc3 + bv.w;
    *reinterpret_cast<float4*>(y + (size_t)(br * 32 + lr) * N_OUT + bc * 32 + lc4 * 4) = o;
}

extern "C" void kernel_launch(void* const* d_in, const int* in_sizes, int n_in,
                              void* d_out, int out_size, void* d_ws, size_t ws_size,
                              hipStream_t stream) {
    const float* x  = (const float*)d_in[0];  // [512, 512]
    const float* w  = (const float*)d_in[1];  // [512, 512]
    const float* b  = (const float*)d_in[2];  // [512]
    float* y        = (float*)d_out;          // [512, 512]

    dim3 grid(N_OUT / 32, /*B=*/512 / 32);    // 16 x 16 = 256 blocks
    memlin_gemm<<<grid, 256, 0, stream>>>(x, w, b, y);
}

// Round 2
// 64.112 us; speedup vs baseline: 1.1138x; 1.1138x over previous
//
#include <hip/hip_runtime.h>

// y = x @ w + b  (the memristive differential-pair mapping cancels exactly:
// G_OFF cancels in even-odd subtraction, K_V and k_cond cancel in the final
// division, so max|weight| is never needed).
//
// Strategy: prep kernel converts x -> bf16 [B][K] and w -> bf16 TRANSPOSED
// [N][K] in d_ws. Then each 16x16x32 bf16 MFMA fragment (A: row=lane&15,
// k=(lane>>4)*8+j ; B: col=lane&15, same k) is one contiguous 16B short8
// load. No LDS, no barriers; 256 single-wave blocks (32x32 tile each).

constexpr int NB   = 512;  // batch
constexpr int NK   = 512;  // n_in
constexpr int NN   = 512;  // n_out

using short8 = __attribute__((ext_vector_type(8))) short;
using f32x4  = __attribute__((ext_vector_type(4))) float;

__device__ inline unsigned short f2bf(float f) {
    // round-to-nearest-even f32 -> bf16
    unsigned u = __builtin_bit_cast(unsigned, f);
    u += 0x7FFFu + ((u >> 16) & 1u);
    return (unsigned short)(u >> 16);
}

// 65536 threads: each converts 4 x-elements (coalesced) and 4 w^T-elements.
__global__ __launch_bounds__(256) void memlin_prep(
    const float* __restrict__ x,   // [B][K]
    const float* __restrict__ w,   // [K][N]
    unsigned short* __restrict__ xb,  // [B][K] bf16
    unsigned short* __restrict__ wt)  // [N][K] bf16 (transposed)
{
    const int t = blockIdx.x * 256 + threadIdx.x;   // 0..65535

    // ---- x convert: element group t*4 ----
    const float4 xv = reinterpret_cast<const float4*>(x)[t];
    ushort4 xo;
    xo.x = f2bf(xv.x); xo.y = f2bf(xv.y); xo.z = f2bf(xv.z); xo.w = f2bf(xv.w);
    reinterpret_cast<ushort4*>(xb)[t] = xo;

    // ---- w transpose: wt[c][k0..k0+4) = w[k0..k0+4)[c] ----
    const int c  = t >> 7;          // 0..511
    const int k0 = (t & 127) * 4;   // 0..508
    ushort4 wo;
    wo.x = f2bf(w[(size_t)(k0 + 0) * NN + c]);
    wo.y = f2bf(w[(size_t)(k0 + 1) * NN + c]);
    wo.z = f2bf(w[(size_t)(k0 + 2) * NN + c]);
    wo.w = f2bf(w[(size_t)(k0 + 3) * NN + c]);
    reinterpret_cast<ushort4*>(wt)[t] = wo;
}

__global__ __launch_bounds__(64) void memlin_gemm(
    const unsigned short* __restrict__ xb,  // [B][K] bf16
    const unsigned short* __restrict__ wt,  // [N][K] bf16
    const float* __restrict__ bias,         // [N]
    float* __restrict__ y)                  // [B][N]
{
    const int l    = threadIdx.x;       // 0..63
    const int row0 = blockIdx.y * 32;
    const int col0 = blockIdx.x * 32;
    const int lr   = l & 15;            // row of A-frag / col of B-frag
    const int kg   = l >> 4;            // k-subgroup: k = kg*8 + j

    f32x4 acc00 = {0.f,0.f,0.f,0.f};
    f32x4 acc01 = {0.f,0.f,0.f,0.f};
    f32x4 acc10 = {0.f,0.f,0.f,0.f};
    f32x4 acc11 = {0.f,0.f,0.f,0.f};

    const unsigned short* xa0 = xb + (size_t)(row0 + lr) * NK + kg * 8;
    const unsigned short* xa1 = xa0 + 16 * NK;
    const unsigned short* wb0 = wt + (size_t)(col0 + lr) * NK + kg * 8;
    const unsigned short* wb1 = wb0 + 16 * NK;

#pragma unroll
    for (int k0 = 0; k0 < NK; k0 += 32) {
        const short8 a0 = *reinterpret_cast<const short8*>(xa0 + k0);
        const short8 a1 = *reinterpret_cast<const short8*>(xa1 + k0);
        const short8 b0 = *reinterpret_cast<const short8*>(wb0 + k0);
        const short8 b1 = *reinterpret_cast<const short8*>(wb1 + k0);
        acc00 = __builtin_amdgcn_mfma_f32_16x16x32_bf16(a0, b0, acc00, 0, 0, 0);
        acc01 = __builtin_amdgcn_mfma_f32_16x16x32_bf16(a0, b1, acc01, 0, 0, 0);
        acc10 = __builtin_amdgcn_mfma_f32_16x16x32_bf16(a1, b0, acc10, 0, 0, 0);
        acc11 = __builtin_amdgcn_mfma_f32_16x16x32_bf16(a1, b1, acc11, 0, 0, 0);
    }

    // C/D layout (verified m89): col = lane&15, row = (lane>>4)*4 + reg
    const float bv0 = bias[col0 + lr];
    const float bv1 = bias[col0 + 16 + lr];

#pragma unroll
    for (int r = 0; r < 4; ++r) {
        const int rowA = row0 + kg * 4 + r;        // from a0 frags
        const int rowB = rowA + 16;                // from a1 frags
        y[(size_t)rowA * NN + col0 + lr]      = acc00[r] + bv0;
        y[(size_t)rowA * NN + col0 + 16 + lr] = acc01[r] + bv1;
        y[(size_t)rowB * NN + col0 + lr]      = acc10[r] + bv0;
        y[(size_t)rowB * NN + col0 + 16 + lr] = acc11[r] + bv1;
    }
}

extern "C" void kernel_launch(void* const* d_in, const int* in_sizes, int n_in,
                              void* d_out, int out_size, void* d_ws, size_t ws_size,
                              hipStream_t stream) {
    const float* x  = (const float*)d_in[0];  // [512, 512]
    const float* w  = (const float*)d_in[1];  // [512, 512]
    const float* b  = (const float*)d_in[2];  // [512]
    float* y        = (float*)d_out;          // [512, 512]

    unsigned short* xb = (unsigned short*)d_ws;            // 512 KiB
    unsigned short* wt = xb + (size_t)NB * NK;             // 512 KiB

    memlin_prep<<<dim3(256), dim3(256), 0, stream>>>(x, w, xb, wt);

    dim3 grid(NN / 32, NB / 32);   // 16 x 16 = 256 single-wave blocks
    memlin_gemm<<<grid, dim3(64), 0, stream>>>(xb, wt, b, y);
}

// Round 3
// 61.562 us; speedup vs baseline: 1.1599x; 1.0414x over previous
//
#include <hip/hip_runtime.h>

// y = x @ w + b  (the memristive differential-pair mapping cancels exactly:
// G_OFF cancels in the even-odd current subtraction; K_V and k_cond cancel
// in the final division, so max|weight| is never needed).
//
// Single fused kernel: 1024 one-wave blocks (grid 32x32), each computes a
// 16x16 output tile with mfma_f32_16x16x32_bf16, converting f32->bf16
// in-register (v_perm pack after +0x8000 round-to-nearest). No LDS, no
// barriers, no prep kernel, full K unroll for ILP.

constexpr int NK = 512;  // n_in
constexpr int NN = 512;  // n_out

using short8 = __attribute__((ext_vector_type(8))) short;
using f32x4  = __attribute__((ext_vector_type(4))) float;

__device__ inline unsigned pack_bf16x2(float f0, float f1) {
    // round-to-nearest (ties up), then pack the two high halves:
    // result = bf16(f1) << 16 | bf16(f0)
    unsigned u0 = __builtin_bit_cast(unsigned, f0) + 0x8000u;
    unsigned u1 = __builtin_bit_cast(unsigned, f1) + 0x8000u;
    return __builtin_amdgcn_perm(u1, u0, 0x07060302u);
}

__global__ __launch_bounds__(64, 1) void memlin_fused(
    const float* __restrict__ x,    // [B][NK]
    const float* __restrict__ w,    // [NK][NN]
    const float* __restrict__ bias, // [NN]
    float* __restrict__ y)          // [B][NN]
{
    const int l    = threadIdx.x;        // 0..63
    const int row0 = blockIdx.y * 16;
    const int col0 = blockIdx.x * 16;
    const int lr   = l & 15;             // A-row / B-col within tile
    const int kg   = l >> 4;             // k-subgroup: k = kg*8 + j

    f32x4 acc = {0.f, 0.f, 0.f, 0.f};

    const float* xrow = x + (size_t)(row0 + lr) * NK + kg * 8;
    const float* wcol = w + (size_t)(kg * 8) * NN + (col0 + lr);

#pragma unroll
    for (int step = 0; step < 16; ++step) {
        const int k0 = step * 32;

        // A fragment: 8 contiguous f32 from x[row][k0+kg*8 ..]
        const float4 a0 = *reinterpret_cast<const float4*>(xrow + k0);
        const float4 a1 = *reinterpret_cast<const float4*>(xrow + k0 + 4);

        // B fragment: 8 strided f32 from w[k][col] (L2-resident)
        const float* wp = wcol + (size_t)k0 * NN;
        float b0 = wp[0 * NN], b1 = wp[1 * NN], b2 = wp[2 * NN], b3 = wp[3 * NN];
        float b4 = wp[4 * NN], b5 = wp[5 * NN], b6 = wp[6 * NN], b7 = wp[7 * NN];

        union { unsigned u[4]; short8 s; } fa, fb;
        fa.u[0] = pack_bf16x2(a0.x, a0.y);
        fa.u[1] = pack_bf16x2(a0.z, a0.w);
        fa.u[2] = pack_bf16x2(a1.x, a1.y);
        fa.u[3] = pack_bf16x2(a1.z, a1.w);
        fb.u[0] = pack_bf16x2(b0, b1);
        fb.u[1] = pack_bf16x2(b2, b3);
        fb.u[2] = pack_bf16x2(b4, b5);
        fb.u[3] = pack_bf16x2(b6, b7);

        acc = __builtin_amdgcn_mfma_f32_16x16x32_bf16(fa.s, fb.s, acc, 0, 0, 0);
    }

    // C/D layout (verified m89): col = lane&15, row = (lane>>4)*4 + reg
    const float bv = bias[col0 + lr];
#pragma unroll
    for (int r = 0; r < 4; ++r) {
        const int row = row0 + kg * 4 + r;
        y[(size_t)row * NN + col0 + lr] = acc[r] + bv;
    }
}

extern "C" void kernel_launch(void* const* d_in, const int* in_sizes, int n_in,
                              void* d_out, int out_size, void* d_ws, size_t ws_size,
                              hipStream_t stream) {
    const float* x  = (const float*)d_in[0];  // [512, 512]
    const float* w  = (const float*)d_in[1];  // [512, 512]
    const float* b  = (const float*)d_in[2];  // [512]
    float* y        = (float*)d_out;          // [512, 512]

    dim3 grid(NN / 16, 512 / 16);   // 32 x 32 = 1024 single-wave blocks
    memlin_fused<<<grid, dim3(64), 0, stream>>>(x, w, b, y);
}